// Round 4
// baseline (150.063 us; speedup 1.0000x reference)
//
#include <hip/hip_runtime.h>
#include <stdint.h>

typedef unsigned short u16;
typedef _Float16 f16;
typedef _Float16 f16x8 __attribute__((ext_vector_type(8)));
typedef float f32x4 __attribute__((ext_vector_type(4)));

#define B_HALF 4096
#define NROWS 8192
#define DCOL 512
#define BMN 256
#define BK 64
#define TT 32            // 8192/256
#define NTILES 528       // TT*(TT+1)/2
#define KT 8             // DCOL/BK

// ---------- kernel A: fused per-row sumsq + fp16 cast + column sums ----------
__global__ __launch_bounds__(256) void prep_kernel(const float* __restrict__ src,
    const float* __restrict__ tgt, u16* __restrict__ hp,
    float* __restrict__ sq, float* __restrict__ colsum) {
  __shared__ float cs[4][DCOL];
  int lane = threadIdx.x & 63, wid = threadIdx.x >> 6;
  float cpart[8] = {0.f,0.f,0.f,0.f,0.f,0.f,0.f,0.f};
  int row0 = blockIdx.x * 16;
#pragma unroll
  for (int r = 0; r < 4; ++r) {
    int row = row0 + r * 4 + wid;
    const float* x = (row < B_HALF) ? (src + (size_t)row * DCOL)
                                    : (tgt + (size_t)(row - B_HALF) * DCOL);
    float4 v0 = *reinterpret_cast<const float4*>(x + lane * 8);
    float4 v1 = *reinterpret_cast<const float4*>(x + lane * 8 + 4);
    float vals[8] = {v0.x, v0.y, v0.z, v0.w, v1.x, v1.y, v1.z, v1.w};
    union { f16 h[8]; uint4 v; } hu;
    float s = 0.f;
#pragma unroll
    for (int q = 0; q < 8; ++q) {
      float f = vals[q];
      s += f * f;
      cpart[q] += f;
      hu.h[q] = (f16)f;        // v_cvt_f16_f32, RNE
    }
    *reinterpret_cast<uint4*>(hp + (size_t)row * DCOL + lane * 8) = hu.v;
#pragma unroll
    for (int o = 32; o > 0; o >>= 1) s += __shfl_down(s, o);
    if (lane == 0) sq[row] = s;
  }
#pragma unroll
  for (int q = 0; q < 8; ++q) cs[wid][lane * 8 + q] = cpart[q];
  __syncthreads();
  int c = threadIdx.x;
  atomicAdd(&colsum[c],       cs[0][c]       + cs[1][c]       + cs[2][c]       + cs[3][c]);
  atomicAdd(&colsum[c + 256], cs[0][c + 256] + cs[1][c + 256] + cs[2][c + 256] + cs[3][c + 256]);
}

// ---------- kernel B: 256x256 8-phase fp16 MFMA Gram + fused bw + fused finalize ----------
#define GLDS(gptr, lptr) __builtin_amdgcn_global_load_lds( \
    (const __attribute__((address_space(1))) void*)(gptr), \
    (__attribute__((address_space(3))) void*)(lptr), 16, 0, 0)

// stage one half-tile (128 rows x 64 cols f16): 2 loads/thread
#define STAGE(S, G, H, KTI, BUF) do { \
    const u16* _g = (G) + (size_t)(H) * 128 * DCOL + (size_t)(KTI) * BK; \
    u16* _l = &S[BUF][((H) * 128 + wid * 8) * BK]; \
    GLDS(_g, _l); \
    GLDS(_g + (size_t)64 * DCOL, _l + 64 * BK); \
  } while (0)

#define PH_TAIL(ACC, BH) \
  __builtin_amdgcn_s_barrier(); \
  asm volatile("s_waitcnt lgkmcnt(0)"); \
  __builtin_amdgcn_s_setprio(1); \
  _Pragma("unroll") \
  for (int mm = 0; mm < 4; ++mm) { \
    _Pragma("unroll") \
    for (int nn = 0; nn < 2; ++nn) { \
      ACC[mm][nn] = __builtin_amdgcn_mfma_f32_16x16x32_f16(a[mm][0], BH[nn][0], ACC[mm][nn], 0, 0, 0); \
      ACC[mm][nn] = __builtin_amdgcn_mfma_f32_16x16x32_f16(a[mm][1], BH[nn][1], ACC[mm][nn], 0, 0, 0); \
    } \
  } \
  __builtin_amdgcn_s_setprio(0); \
  __builtin_amdgcn_s_barrier();

__global__ __launch_bounds__(512, 2) void mmd_gemm_kernel(
    const u16* __restrict__ hp,
    const float* __restrict__ sq, const float* __restrict__ colsum,
    float* __restrict__ partials, unsigned int* __restrict__ counter,
    float* __restrict__ out) {
  __shared__ __align__(16) u16 sA[2][BMN * BK];   // 2 x 32 KB
  __shared__ __align__(16) u16 sB[2][BMN * BK];   // 2 x 32 KB
  __shared__ float sqR[BMN], sqC[BMN];
  __shared__ double redS[8], redC[8];
  __shared__ int isLast;

  // bijective XCD swizzle (528 % 8 == 0), then linear-index -> triangle (I<=J)
  int bid = blockIdx.x;
  int t6 = (bid & 7) * (NTILES / 8) + (bid >> 3);
  int I = 0, rem = t6;
  while (rem >= TT - I) { rem -= TT - I; ++I; }
  int J = I + rem;
  int rowStart = I * BMN, colStart = J * BMN;

  int tid = threadIdx.x;
  int lane = tid & 63, wid = tid >> 6;
  int wr = wid >> 2, wc = wid & 3;           // 2 x 4 waves; per-wave out 128x64

  // per-lane staging sources (row slab wid*8, pre-swizzled chunk)
  const u16* gA = hp + (size_t)(rowStart + wid * 8 + (lane >> 3)) * DCOL
                     + ((lane & 7) ^ (lane >> 3)) * 8;
  const u16* gB = hp + (size_t)(colStart + wid * 8 + (lane >> 3)) * DCOL
                     + ((lane & 7) ^ (lane >> 3)) * 8;

  // fragment LDS offsets (f16 units); swizzle XOR matches staging
  int r15 = lane & 15, kg = lane >> 4;
  int aOff = (wr * 64 + r15) * BK;
  int bOff = (wc * 32 + r15) * BK;
  int co0 = ((kg) ^ (lane & 7)) * 8;         // kk=0
  int co1 = ((4 + kg) ^ (lane & 7)) * 8;     // kk=1

  // ---- prologue: stage stream prefix 0A0 0B0 0A1 0B1 1A0 1B0 1A1 ----
  STAGE(sA, gA, 0, 0, 0);
  STAGE(sB, gB, 0, 0, 0);
  STAGE(sA, gA, 1, 0, 0);
  STAGE(sB, gB, 1, 0, 0);
  STAGE(sA, gA, 0, 1, 1);
  STAGE(sB, gB, 0, 1, 1);
  STAGE(sA, gA, 1, 1, 1);

  // sq tiles to LDS (overlaps with staging latency)
  if (tid < 256) sqR[tid] = sq[rowStart + tid];
  else           sqC[tid - 256] = sq[colStart + (tid - 256)];

  // in-block bandwidth: bw = (2n*sum(sq) - 2*sum(colsum^2)) / (n^2-n)
  double ssq = 0.0;
#pragma unroll
  for (int k2 = 0; k2 < 16; ++k2) ssq += (double)sq[tid + 512 * k2];
  double c0 = (double)colsum[tid];
  double scs = c0 * c0;
#pragma unroll
  for (int o = 32; o > 0; o >>= 1) {
    ssq += __shfl_down(ssq, o);
    scs += __shfl_down(scs, o);
  }
  if (lane == 0) { redS[wid] = ssq; redC[wid] = scs; }
  __syncthreads();            // also drains prologue staging (vmcnt 0)
  double S = 0.0, C2 = 0.0;
#pragma unroll
  for (int w = 0; w < 8; ++w) { S += redS[w]; C2 += redC[w]; }
  double nn_ = 8192.0;
  double bwv = (2.0 * nn_ * S - 2.0 * C2) / (nn_ * nn_ - nn_);
  float gf = (float)(-1.0 / (16.0 * bwv));

  f16x8 a[4][2], b0[2][2], b1[2][2];
  f32x4 acc00[4][2], acc01[4][2], acc11[4][2], acc10[4][2];
#pragma unroll
  for (int mm = 0; mm < 4; ++mm)
#pragma unroll
    for (int nn = 0; nn < 2; ++nn) {
      acc00[mm][nn] = (f32x4){0.f,0.f,0.f,0.f};
      acc01[mm][nn] = (f32x4){0.f,0.f,0.f,0.f};
      acc11[mm][nn] = (f32x4){0.f,0.f,0.f,0.f};
      acc10[mm][nn] = (f32x4){0.f,0.f,0.f,0.f};
    }

  // ---- main loop: 8 K-tiles x 4 phases ----
#pragma unroll
  for (int t = 0; t < KT; ++t) {
    const int buf = t & 1, nbuf = buf ^ 1;
    // P1: read A-half0 (8 b128) + B-half0 (4 b128); stage (t+1):B1; MFMA (mh0,nh0)
#pragma unroll
    for (int mm = 0; mm < 4; ++mm) {
      a[mm][0] = *(const f16x8*)&sA[buf][aOff + mm * 1024 + co0];
      a[mm][1] = *(const f16x8*)&sA[buf][aOff + mm * 1024 + co1];
    }
#pragma unroll
    for (int nn = 0; nn < 2; ++nn) {
      b0[nn][0] = *(const f16x8*)&sB[buf][bOff + nn * 1024 + co0];
      b0[nn][1] = *(const f16x8*)&sB[buf][bOff + nn * 1024 + co1];
    }
    if (t + 1 < KT) STAGE(sB, gB, 1, t + 1, nbuf);
    PH_TAIL(acc00, b0)
    // P2: read B-half1 (4); stage (t+2):A0; MFMA (mh0,nh1)
#pragma unroll
    for (int nn = 0; nn < 2; ++nn) {
      b1[nn][0] = *(const f16x8*)&sB[buf][8192 + bOff + nn * 1024 + co0];
      b1[nn][1] = *(const f16x8*)&sB[buf][8192 + bOff + nn * 1024 + co1];
    }
    if (t + 2 < KT) STAGE(sA, gA, 0, t + 2, buf);
    PH_TAIL(acc01, b1)
    // P3: read A-half1 (8); stage (t+2):B0; MFMA (mh1,nh1)
#pragma unroll
    for (int mm = 0; mm < 4; ++mm) {
      a[mm][0] = *(const f16x8*)&sA[buf][8192 + aOff + mm * 1024 + co0];
      a[mm][1] = *(const f16x8*)&sA[buf][8192 + aOff + mm * 1024 + co1];
    }
    if (t + 2 < KT) STAGE(sB, gB, 0, t + 2, buf);
    PH_TAIL(acc11, b1)
    // P4: stage (t+2):A1; counted vmcnt (never 0 until drain); MFMA (mh1,nh0)
    if (t + 2 < KT) STAGE(sA, gA, 1, t + 2, buf);
    if (t < KT - 2)       { asm volatile("s_waitcnt vmcnt(6)" ::: "memory"); }
    else if (t == KT - 2) { asm volatile("s_waitcnt vmcnt(0)" ::: "memory"); }
    PH_TAIL(acc10, b0)
  }

  // ---- fused epilogue: l2 -> u + u^2 + u^4 + u^8 + u^16, u = exp(-l2/(16bw)) ----
  float partial = 0.f;
#define EPI(ACC, MH, NH) \
  _Pragma("unroll") for (int mm = 0; mm < 4; ++mm) \
  _Pragma("unroll") for (int nn = 0; nn < 2; ++nn) \
  _Pragma("unroll") for (int e = 0; e < 4; ++e) { \
    float sr = sqR[(MH) * 128 + wr * 64 + mm * 16 + (lane >> 4) * 4 + e]; \
    float sc = sqC[(NH) * 128 + wc * 32 + nn * 16 + (lane & 15)]; \
    float l2v = sr + sc - 2.f * ACC[mm][nn][e]; \
    float u = __expf(gf * l2v); \
    float u2 = u * u, u4 = u2 * u2, u8 = u4 * u4, u16v = u8 * u8; \
    partial += u + u2 + u4 + u8 + u16v; }
  EPI(acc00, 0, 0)
  EPI(acc01, 0, 1)
  EPI(acc11, 1, 1)
  EPI(acc10, 1, 0)

  float wsign = ((I == J) ? 1.f : 2.f) *
                (((rowStart < B_HALF) == (colStart < B_HALF)) ? 1.f : -1.f);
  partial *= wsign;
#pragma unroll
  for (int o = 32; o > 0; o >>= 1) partial += __shfl_down(partial, o);
  if (lane == 0) partials[bid * 8 + wid] = partial;

  // ---- fused finalize: last block reduces all partials deterministically ----
  __threadfence();
  __syncthreads();
  if (tid == 0) isLast = (atomicAdd(counter, 1u) == NTILES - 1);
  __syncthreads();
  if (isLast) {
    __threadfence();
    double s = 0.0;
    for (int i = tid; i < NTILES * 8; i += 512) s += (double)partials[i];
#pragma unroll
    for (int o = 32; o > 0; o >>= 1) s += __shfl_down(s, o);
    if (lane == 0) redS[wid] = s;
    __syncthreads();
    if (tid == 0) {
      double tot = 0.0;
#pragma unroll
      for (int w = 0; w < 8; ++w) tot += redS[w];
      out[0] = (float)(tot / (4096.0 * 4096.0));
    }
  }
}

extern "C" void kernel_launch(void* const* d_in, const int* in_sizes, int n_in,
                              void* d_out, int out_size, void* d_ws, size_t ws_size,
                              hipStream_t stream) {
  const float* src = (const float*)d_in[0];
  const float* tgt = (const float*)d_in[1];
  char* ws = (char*)d_ws;

  float*        colsum   = (float*)(ws + 0);        // 512 f32 (memset to 0)
  unsigned int* counter  = (unsigned int*)(ws + 2048);
  float*        sqp      = (float*)(ws + 4096);     // 8192 f32
  float*        partials = (float*)(ws + 36864);    // 528*8 f32
  u16*          hp       = (u16*)(ws + 65536);      // 8192*512 fp16 = 8.39 MB

  hipMemsetAsync(ws, 0, 4096, stream);              // zero colsum + counter

  prep_kernel<<<NROWS / 16, 256, 0, stream>>>(src, tgt, hp, sqp, colsum);
  mmd_gemm_kernel<<<NTILES, 512, 0, stream>>>(hp, sqp, colsum, partials,
                                              counter, (float*)d_out);
}